// Round 6
// baseline (324.112 us; speedup 1.0000x reference)
//
#include <hip/hip_runtime.h>
#include <hip/hip_bf16.h>

#define IN_F 256
#define NN   2048
#define BB   8

typedef unsigned short u16;
typedef __attribute__((ext_vector_type(8))) short short8x;   // 8 bf16 = 4 VGPRs
typedef __attribute__((ext_vector_type(4))) float float4x;   // MFMA acc

// fp32 -> bf16 bits, round-to-nearest-even
__device__ __forceinline__ u16 f2b(float f) {
    union { float f; unsigned int u; } x; x.f = f;
    unsigned int r = x.u + 0x7FFFu + ((x.u >> 16) & 1u);
    return (u16)(r >> 16);
}

// ---------------------------------------------------------------------------
// prep: fused transposes (h->HbfT, lrgt1->GbfT, W1->W1T, W2->W2T) + calc_v.
// ---------------------------------------------------------------------------
__device__ __forceinline__ void transp_body(const float* __restrict__ src,
                                            u16* __restrict__ dst,
                                            int R, int C, int tid,
                                            float (*tile)[33])
{
    const int per = (R / 32) * (C / 32);
    const int b  = tid / per;
    const int tt = tid % per;
    const int jt = tt / (C / 32);
    const int ct = tt % (C / 32);
    src += (long)b * R * C;
    dst += (long)b * R * C;

    const int tx = threadIdx.x & 31, ty = threadIdx.x >> 5;
#pragma unroll
    for (int i = 0; i < 4; ++i)
        tile[ty + i * 8][tx] = src[(long)(jt * 32 + ty + i * 8) * C + ct * 32 + tx];
    __syncthreads();
#pragma unroll
    for (int i = 0; i < 4; ++i)
        dst[(long)(ct * 32 + ty + i * 8) * R + jt * 32 + tx] = f2b(tile[tx][ty + i * 8]);
}

__global__ __launch_bounds__(256) void prep(const float* __restrict__ h,
                                            const float* __restrict__ g,
                                            const float* __restrict__ W1,
                                            const float* __restrict__ W2,
                                            const float* __restrict__ a,
                                            u16* __restrict__ HbfT,
                                            u16* __restrict__ GbfT,
                                            u16* __restrict__ W1T,
                                            u16* __restrict__ W2T,
                                            float* __restrict__ v1,
                                            float* __restrict__ v2)
{
    __shared__ float tile[32][33];
    __shared__ float s1[IN_F], s2[IN_F];
    const int bid = blockIdx.x;

    if (bid < 4096) {
        transp_body(h, HbfT, NN, IN_F, bid, tile);
    } else if (bid < 8192) {
        transp_body(g, GbfT, NN, IN_F, bid - 4096, tile);
    } else if (bid < 8256) {
        transp_body(W1, W1T, IN_F, IN_F, bid - 8192, tile);
    } else if (bid < 8320) {
        transp_body(W2, W2T, IN_F, IN_F, bid - 8256, tile);
    } else {
        const int t = threadIdx.x;
        s1[t] = a[t];
        s2[t] = a[IN_F + t];
        __syncthreads();
        float acc1 = 0.f, acc2 = 0.f;
        for (int c = 0; c < IN_F; ++c) {
            float w = W1[t * IN_F + c];
            acc1 += w * s1[c];
            acc2 += w * s2[c];
        }
        v1[t] = acc1;
        v2[t] = acc2;
    }
}

// ---------------------------------------------------------------------------
// rowdots: Wh1[row] = h[row,:]·v1, Wh2[row] = h[row,:]·v2. One wave per row.
// ---------------------------------------------------------------------------
__global__ __launch_bounds__(256) void rowdots(const float* __restrict__ h,
                                               const float* __restrict__ v1,
                                               const float* __restrict__ v2,
                                               float* __restrict__ Wh1,
                                               float* __restrict__ Wh2)
{
    const int wave = threadIdx.x >> 6;
    const int lane = threadIdx.x & 63;
    const long row = (long)blockIdx.x * 4 + wave;
    const int c0 = lane * 4;

    float4 v  = *(const float4*)(h + row * IN_F + c0);
    float4 a1 = *(const float4*)(v1 + c0);
    float4 a2 = *(const float4*)(v2 + c0);

    float s1 = v.x * a1.x + v.y * a1.y + v.z * a1.z + v.w * a1.w;
    float s2 = v.x * a2.x + v.y * a2.y + v.z * a2.z + v.w * a2.w;
#pragma unroll
    for (int off = 32; off; off >>= 1) {
        s1 += __shfl_xor(s1, off, 64);
        s2 += __shfl_xor(s2, off, 64);
    }
    if (lane == 0) { Wh1[row] = s1; Wh2[row] = s2; }
}

// ---------------------------------------------------------------------------
// attn_mfma v7: matrix-split blocks — 2 INDEPENDENT blocks per CU.
// Ledger: queue-position (v6), barrier-drain (v2), L2-locality (v2) all
// falsified; v3's schedule is kept verbatim.  The remaining structural fact:
// grid=256 put exactly ONE 8-wave barrier-lockstep block on each CU — when
// it stalled on B/adj latency the CU idled (no independent work).  Fix:
// split each row-block into an H-block and a G-block (grid 512, 256 thr,
// 4 waves, 64 rows x 256 cols of ONE matrix).  2 independent blocks/CU:
// one block's MFMA/VALU fills the other's latency stalls.  Costs: P/exp
// compute duplicated x2 (VALU is only ~14% busy), adj logically read twice
// (H/G pair is dispatch-adjacent on the same XCD -> 2nd read L2-hits).
// Wh2 is staged to LDS once (8 KB) — removes the w4 register buffers.
// Schedule per chunk (v3-proven): p-compute(adj regs + wh2 LDS) ->
// mid-chunk distance-1 adj prefetch -> A-writes -> lgkm-only barrier ->
// 4 ksteps {AREAD, 16 MFMA, B ping-pong issue}.
// ---------------------------------------------------------------------------
#define KSTEP(ksv, BC, BN_, AC, AN_, do_a, jnxt)                              \
    {                                                                         \
        if (do_a) {                                                           \
            _Pragma("unroll") for (int rt = 0; rt < 4; ++rt)                  \
                AN_[rt] = *(const short8x*)&ab[(((ksv) + 1) * 4 + rt) * 512 + lane * 8]; \
        }                                                                     \
        _Pragma("unroll") for (int ct = 0; ct < 4; ++ct)                      \
            BN_[ct] = *(const short8x*)(Bp + ct * 16 * NN + (jnxt));          \
        _Pragma("unroll") for (int rt = 0; rt < 4; ++rt)                      \
            _Pragma("unroll") for (int ct = 0; ct < 4; ++ct)                  \
                acc[rt][ct] = __builtin_amdgcn_mfma_f32_16x16x32_bf16(AC[rt], BC[ct], acc[rt][ct], 0, 0, 0); \
    }

#define CHUNK7(KCH, ADJC, ADJN)                                               \
    {                                                                         \
        const int j0 = (KCH) * 128;                                           \
        union { short8x v; u16 e[8]; } pk0, pk1, pk2, pk3;                    \
        _Pragma("unroll") for (int u = 0; u < 8; ++u) {                       \
            const float4 wv = *(const float4*)&wh2L[j0 + sg * 32 + u * 4];    \
            const float wf[4] = {wv.x, wv.y, wv.z, wv.w};                     \
            const int   av[4] = {ADJC[u].x, ADJC[u].y, ADJC[u].z, ADJC[u].w}; \
            _Pragma("unroll") for (int c = 0; c < 4; ++c) {                   \
                float x = wh1rr + wf[c];                                      \
                float ev = fmaxf(x, 0.2f * x);                                \
                float p = __expf(ev - mv);                                    \
                p = (av[c] > 0) ? p : 0.0f;                                   \
                lloc += p;                                                    \
                u16 fv = f2b(p);                                              \
                if (u < 2)      pk0.e[(u & 1) * 4 + c] = fv;                  \
                else if (u < 4) pk1.e[(u & 1) * 4 + c] = fv;                  \
                else if (u < 6) pk2.e[(u & 1) * 4 + c] = fv;                  \
                else            pk3.e[(u & 1) * 4 + c] = fv;                  \
            }                                                                 \
        }                                                                     \
        if ((KCH) < 15) {                                                     \
            const long o = adjR + ((KCH) + 1) * 128 + sg * 32;                \
            _Pragma("unroll") for (int u = 0; u < 8; ++u)                     \
                ADJN[u] = *(const int4*)(adj + o + u * 4);                    \
        }                                                                     \
        u16* ab = &Afrag[(KCH) & 1][0];                                       \
        *(short8x*)&ab[wbase0]       = pk0.v;                                 \
        *(short8x*)&ab[wbase0 + 128] = pk1.v;                                 \
        *(short8x*)&ab[wbase0 + 256] = pk2.v;                                 \
        *(short8x*)&ab[wbase0 + 384] = pk3.v;                                 \
        asm volatile("s_waitcnt lgkmcnt(0)\n\ts_barrier" ::: "memory");       \
        _Pragma("unroll") for (int rt = 0; rt < 4; ++rt)                      \
            A0[rt] = *(const short8x*)&ab[rt * 512 + lane * 8];               \
        KSTEP(0, B0, B1, A0, A1, 1, j0 + 1 * 32 + bq8)                        \
        KSTEP(1, B1, B0, A1, A0, 1, j0 + 2 * 32 + bq8)                        \
        KSTEP(2, B0, B1, A0, A1, 1, j0 + 3 * 32 + bq8)                        \
        KSTEP(3, B1, B0, A1, A0, 0, (((KCH) < 15) ? (j0 + 128) : j0) + bq8)   \
    }

__global__ __launch_bounds__(256, 2) void attn_mfma(
    const int* __restrict__ adj,
    const u16* __restrict__ HbfT, const u16* __restrict__ GbfT,
    const float* __restrict__ Wh1, const float* __restrict__ Wh2,
    u16* __restrict__ PH, u16* __restrict__ PG)
{
    const int t = threadIdx.x;
    const int wave = t >> 6, lane = t & 63;
    // bid -> (batch=XCD, row-block, matrix).  H/G pair = bids 8 apart:
    // same XCD under round-robin dispatch, adjacent in dispatch order ->
    // the pair's shared adj slice L2-hits on the second reader.
    const int b   = blockIdx.x & 7;
    const int idx = blockIdx.x >> 3;           // [0,64) within batch
    const int mat = idx & 1;                   // 0 = H, 1 = G
    const int rbl = idx >> 1;                  // [0,32) row-block in batch
    const long gi0 = ((long)b * 32 + rbl) * 64;

    __shared__ __align__(16) u16 Afrag[2][8192];   // 2 x 16 KB
    __shared__ float wh2L[2048];                   // 8 KB: batch Wh2 slice
    __shared__ float sred[256];
    __shared__ float ssc[65];                      // [0..63]=1/l, [64]=wh2max

    // p-compute role: row rr (64 rows), sg (4) -> 32 consecutive j per chunk
    const int rr = t >> 2, sg = t & 3;
    const long adjR = (gi0 + rr) * (long)NN;
    const float* wh2b = Wh2 + (long)b * NN;
    const float wh1rr = Wh1[gi0 + rr];

    // ---- stage Wh2 slice to LDS + per-batch max ----
    {
        float4 w0 = *(const float4*)(wh2b + t * 8);
        float4 w1 = *(const float4*)(wh2b + t * 8 + 4);
        *(float4*)&wh2L[t * 8]     = w0;
        *(float4*)&wh2L[t * 8 + 4] = w1;
        float m = fmaxf(fmaxf(fmaxf(w0.x, w0.y), fmaxf(w0.z, w0.w)),
                        fmaxf(fmaxf(w1.x, w1.y), fmaxf(w1.z, w1.w)));
        sred[t] = m;
    }
    __syncthreads();
    if (t < 64) {
        float v = fmaxf(fmaxf(sred[t * 4], sred[t * 4 + 1]),
                        fmaxf(sred[t * 4 + 2], sred[t * 4 + 3]));
#pragma unroll
        for (int off = 32; off; off >>= 1) v = fmaxf(v, __shfl_xor(v, off, 64));
        if (t == 0) ssc[64] = v;
    }
    __syncthreads();
    const float mm = wh1rr + ssc[64];
    const float mv = (mm >= 0.f) ? mm : 0.2f * mm;   // lrelu upper bound >= all logits

    // A-fragment write slot: thread (rr, sg=kstep) covers k = sg*32+e,
    // e in [0,32); frag f = sg*4 + (rr>>4); lane (rr&15)+16q holds e=q*8..+7.
    const int wbase0 = (sg * 4 + (rr >> 4)) * 512 + (rr & 15) * 8;

    float4x acc[4][4];
#pragma unroll
    for (int rt = 0; rt < 4; ++rt)
#pragma unroll
        for (int ct = 0; ct < 4; ++ct) acc[rt][ct] = (float4x)0.0f;

    const int bn = lane & 15, bq = lane >> 4, bq8 = bq * 8;
    // wave -> 64-col slice of this block's matrix
    const u16* Bp = (mat ? GbfT : HbfT) + (long)b * IN_F * NN
                  + (long)(wave * 64 + bn) * NN;

    float lloc = 0.f;

    short8x A0[4], A1[4], B0[4], B1[4];
    int4 adjA[8], adjB[8];

    // ---- prologue: adj for chunks 0 and 1; B group (kch=0, ks=0) ----
#pragma unroll
    for (int u = 0; u < 8; ++u)
        adjA[u] = *(const int4*)(adj + adjR + sg * 32 + u * 4);
#pragma unroll
    for (int u = 0; u < 8; ++u)
        adjB[u] = *(const int4*)(adj + adjR + 128 + sg * 32 + u * 4);
#pragma unroll
    for (int ct = 0; ct < 4; ++ct)
        B0[ct] = *(const short8x*)(Bp + ct * 16 * NN + bq8);

    for (int kp = 0; kp < 8; ++kp) {
        CHUNK7(kp * 2,     adjA, adjB)
        CHUNK7(kp * 2 + 1, adjB, adjA)
    }

    // ---- reduce l per row (4 partials/row), invert ----
    sred[t] = lloc;
    __syncthreads();
    if (t < 64) {
        float v = sred[t * 4] + sred[t * 4 + 1] + sred[t * 4 + 2] + sred[t * 4 + 3];
        ssc[t] = 1.0f / v;       // v > 0 always (~half the j's unmasked)
    }
    __syncthreads();

    // ---- scale by 1/l and store (C-layout: col=lane&15, row=(lane>>4)*4+reg)
    u16* dst = mat ? PG : PH;
    const int colb = wave * 64;
#pragma unroll
    for (int rt = 0; rt < 4; ++rt)
#pragma unroll
        for (int ct = 0; ct < 4; ++ct) {
            const int c = colb + ct * 16 + bn;
#pragma unroll
            for (int reg = 0; reg < 4; ++reg) {
                const int rl = rt * 16 + bq * 4 + reg;
                const float il = ssc[rl];
                const long row = gi0 + rl;
                dst[row * IN_F + c] = f2b(acc[rt][ct][reg] * il);
            }
        }
}

// ---------------------------------------------------------------------------
// epi2: both epilogue GEMMs in one launch.
// blocks [0,512): out0 = ELU(PH @ W1); blocks [512,1024): out1 = ELU(PG @ W2)
// ---------------------------------------------------------------------------
__global__ __launch_bounds__(256) void epi2(const u16* __restrict__ PH,
                                            const u16* __restrict__ PG,
                                            const u16* __restrict__ W1T,
                                            const u16* __restrict__ W2T,
                                            float* __restrict__ out)
{
    int bid = blockIdx.x;
    const u16* X;
    const u16* WT;
    float* o;
    if (bid < 512) { X = PH; WT = W1T; o = out; }
    else           { X = PG; WT = W2T; o = out + (long)BB * NN * IN_F; bid -= 512; }

    const int t = threadIdx.x;
    const int wave = t >> 6, lane = t & 63;
    const long i0 = (long)bid * 32;

    __shared__ __align__(16) u16 Afrag[8 * 2 * 64 * 8];   // 16 KB

    const int m = t >> 3, ks0 = t & 7, rt0 = m >> 4, lm = m & 15;
    const u16* xp = X + (i0 + m) * IN_F + ks0 * 32;
#pragma unroll
    for (int q = 0; q < 4; ++q) {
        short8x v = *(const short8x*)(xp + q * 8);
        *(short8x*)&Afrag[((ks0 * 2 + rt0) * 64 + lm + q * 16) * 8] = v;
    }
    __syncthreads();

    float4x acc[2][4];
#pragma unroll
    for (int rt = 0; rt < 2; ++rt)
#pragma unroll
        for (int ct = 0; ct < 4; ++ct) acc[rt][ct] = (float4x)0.0f;

    const int bn = lane & 15, bq = lane >> 4;
#pragma unroll
    for (int ks = 0; ks < 8; ++ks) {
        short8x A0 = *(const short8x*)&Afrag[((ks * 2 + 0) * 64 + lane) * 8];
        short8x A1 = *(const short8x*)&Afrag[((ks * 2 + 1) * 64 + lane) * 8];
#pragma unroll
        for (int ct = 0; ct < 4; ++ct) {
            const int n = wave * 64 + ct * 16 + bn;
            short8x Bw = *(const short8x*)(WT + n * IN_F + ks * 32 + bq * 8);
            acc[0][ct] = __builtin_amdgcn_mfma_f32_16x16x32_bf16(A0, Bw, acc[0][ct], 0, 0, 0);
            acc[1][ct] = __builtin_amdgcn_mfma_f32_16x16x32_bf16(A1, Bw, acc[1][ct], 0, 0, 0);
        }
    }

#pragma unroll
    for (int rt = 0; rt < 2; ++rt)
#pragma unroll
        for (int ct = 0; ct < 4; ++ct) {
            const int n = wave * 64 + ct * 16 + bn;
#pragma unroll
            for (int reg = 0; reg < 4; ++reg) {
                const long row = i0 + rt * 16 + bq * 4 + reg;
                float v = acc[rt][ct][reg];
                v = (v > 0.f) ? v : (__expf(v) - 1.f);   // ELU
                o[row * IN_F + n] = v;
            }
        }
}

// ---------------------------------------------------------------------------
extern "C" void kernel_launch(void* const* d_in, const int* in_sizes, int n_in,
                              void* d_out, int out_size, void* d_ws, size_t ws_size,
                              hipStream_t stream)
{
    int ih = -1, ig = -1, iadj = -1, iw1 = -1, iw2 = -1, ia = -1;
    for (int i = 0; i < n_in; ++i) {
        int s = in_sizes[i];
        if      (s == BB * NN * NN)   { if (iadj < 0) iadj = i; }
        else if (s == BB * NN * IN_F) { if (ih < 0) ih = i; else if (ig < 0) ig = i; }
        else if (s == IN_F * IN_F)    { if (iw1 < 0) iw1 = i; else if (iw2 < 0) iw2 = i; }
        else if (s == 2 * IN_F)       { if (ia < 0) ia = i; }
    }
    if (ih < 0 || ig < 0 || iadj < 0 || iw1 < 0 || iw2 < 0 || ia < 0) {
        ih = 0; iadj = 1; ig = 2; iw1 = 3; iw2 = 4; ia = 5;
    }
    const float* h     = (const float*)d_in[ih];
    const int*   adj   = (const int*)  d_in[iadj];
    const float* lrgt1 = (const float*)d_in[ig];
    const float* W1    = (const float*)d_in[iw1];
    const float* W2    = (const float*)d_in[iw2];
    const float* a     = (const float*)d_in[ia];
    float* out = (float*)d_out;

    // ws layout — 33,949,696 B total (<= proven-available 34,212,096 B)
    float* ws   = (float*)d_ws;
    float* v1   = ws;                       // 256
    float* v2   = v1 + IN_F;                // 256
    float* Wh1  = v2 + IN_F;                // 16384
    float* Wh2  = Wh1 + BB * NN;            // 16384
    u16* W1T  = (u16*)(Wh2 + BB * NN);      // 65536 bf16
    u16* W2T  = W1T + IN_F * IN_F;          // 65536
    u16* HbfT = W2T + IN_F * IN_F;          // 8*256*2048
    u16* GbfT = HbfT + (long)BB * IN_F * NN;
    u16* PH   = GbfT + (long)BB * IN_F * NN;
    u16* PG   = PH + (long)BB * NN * IN_F;

    const int nrows = BB * NN;

    prep     <<<8321,        256, 0, stream>>>(h, lrgt1, W1, W2, a,
                                               HbfT, GbfT, W1T, W2T, v1, v2);
    rowdots  <<<nrows / 4,   256, 0, stream>>>(h, v1, v2, Wh1, Wh2);
    attn_mfma<<<nrows / 32,  256, 0, stream>>>(adj, HbfT, GbfT, Wh1, Wh2, PH, PG);
    epi2     <<<2 * nrows / 32, 256, 0, stream>>>(PH, PG, W1T, W2T, out);
}